// Round 5
// baseline (99.141 us; speedup 1.0000x reference)
//
#include <hip/hip_runtime.h>
#include <hip/hip_bf16.h>
#include <stdint.h>

#define N 4096
#define D 512
#define TILE 128
#define KITERS 4         // K=512 in 4 chunks of 128 (one MX MFMA each)
#define NB (N / TILE)    // 32

typedef float f32x4 __attribute__((ext_vector_type(4)));
typedef int   i32x8 __attribute__((ext_vector_type(8)));
typedef int   i32x4 __attribute__((ext_vector_type(4)));

// ---------------------------------------------------------------------------
// Kernel 1: fp32 -> fp8 e4m3 (OCP) conversion + fp32 row squared-norms.
// One wave per row: 512 elems / 64 lanes = 8 elems/lane (one 8B store).
// Norms are exact fp32; only the Gram term carries fp8 error.
// ---------------------------------------------------------------------------
__global__ __launch_bounds__(256) void prep_kernel(const float* __restrict__ x,
                                                   unsigned char* __restrict__ xq,
                                                   float* __restrict__ sq) {
    int row  = blockIdx.x * 4 + (threadIdx.x >> 6);
    int lane = threadIdx.x & 63;
    const float* xr = x + (size_t)row * D + lane * 8;
    float4 v0 = *reinterpret_cast<const float4*>(xr);
    float4 v1 = *reinterpret_cast<const float4*>(xr + 4);

    int w0 = __builtin_amdgcn_cvt_pk_fp8_f32(v0.x, v0.y, 0, false);
    w0     = __builtin_amdgcn_cvt_pk_fp8_f32(v0.z, v0.w, w0, true);
    int w1 = __builtin_amdgcn_cvt_pk_fp8_f32(v1.x, v1.y, 0, false);
    w1     = __builtin_amdgcn_cvt_pk_fp8_f32(v1.z, v1.w, w1, true);
    reinterpret_cast<int2*>(xq + (size_t)row * D)[lane] = make_int2(w0, w1);

    float s = v0.x * v0.x + v0.y * v0.y + v0.z * v0.z + v0.w * v0.w +
              v1.x * v1.x + v1.y * v1.y + v1.z * v1.z + v1.w * v1.w;
    #pragma unroll
    for (int off = 32; off > 0; off >>= 1) s += __shfl_down(s, off);
    if (lane == 0) sq[row] = s;
}

// ---------------------------------------------------------------------------
// Kernel 2: lower-triangle Gram via MX-scaled fp8 MFMA (K=128, unit scales)
// + fused distance epilogue. 128x128 tile, 4 waves each owning 64x64.
//
// NO LDS, NO BARRIERS: xq is 2 MB = fully L2-resident, so each wave loads
// its MFMA fragments directly from global/L2. The A-operand layout
// A[m=lr][k=quad*32+0..31] means the fragment's two b128 loads together
// read full 128-B rows (16 rows x 128 B per fragment pair) -> coalesced.
// This removes the R1-R4 structural stall (per-iter s_waitcnt vmcnt(0)
// barrier drains) entirely; loads pipeline across the unrolled K-loop under
// compiler-issued fine-grained vmcnt, hidden by 16 MFMA x ~35 cyc per iter.
// Read amplification vs LDS staging: 2x (A,B each read by 2 of 4 waves)
// = 135 MB total from L2 at 34.5 TB/s ~= 3.9 us -- affordable; we were
// latency-bound, not BW-bound.
// ---------------------------------------------------------------------------
__global__ __launch_bounds__(256, 2) void pairdist_kernel(const unsigned char* __restrict__ xq,
                                                          const float* __restrict__ sq,
                                                          float* __restrict__ out) {
    // Linear block id -> (bi, bj) with bj <= bi (528 lower-triangular pairs)
    int t  = blockIdx.x;
    int bi = (int)((sqrtf(8.0f * (float)t + 1.0f) - 1.0f) * 0.5f);
    while ((bi + 1) * (bi + 2) / 2 <= t) bi++;
    while (bi * (bi + 1) / 2 > t) bi--;
    int bj = t - bi * (bi + 1) / 2;

    int tid  = threadIdx.x;
    int w    = tid >> 6;        // wave 0..3
    int lane = tid & 63;
    int quad = lane >> 4;       // 0..3
    int lr   = lane & 15;       // 0..15
    int wm   = w >> 1;          // wave row (0..1) -> 64 rows
    int wn   = w & 1;           // wave col (0..1) -> 64 cols

    int ibase = bi * TILE + wm * 64;
    int jbase = bj * TILE + wn * 64;

    f32x4 acc[4][4];
    #pragma unroll
    for (int mt = 0; mt < 4; mt++)
        #pragma unroll
        for (int nt = 0; nt < 4; nt++)
            acc[mt][nt] = (f32x4)0.0f;

    // Per-fragment row pointers: lane (lr, quad) reads row (base + mt*16+lr),
    // bytes [quad*32, quad*32+32) of each 128-B K-chunk.
    const unsigned char* pa[4];
    const unsigned char* pb[4];
    #pragma unroll
    for (int mt = 0; mt < 4; mt++)
        pa[mt] = xq + (size_t)(ibase + mt * 16 + lr) * D + quad * 32;
    #pragma unroll
    for (int nt = 0; nt < 4; nt++)
        pb[nt] = xq + (size_t)(jbase + nt * 16 + lr) * D + quad * 32;

    #pragma unroll
    for (int it = 0; it < KITERS; ++it) {
        const int k0 = it * 128;  // folds into 13-bit signed load offsets
        i32x8 af[4], bfr[4];
        #pragma unroll
        for (int mt = 0; mt < 4; mt++) {
            i32x4 lo = *reinterpret_cast<const i32x4*>(pa[mt] + k0);
            i32x4 hi = *reinterpret_cast<const i32x4*>(pa[mt] + k0 + 16);
            af[mt][0] = lo[0]; af[mt][1] = lo[1]; af[mt][2] = lo[2]; af[mt][3] = lo[3];
            af[mt][4] = hi[0]; af[mt][5] = hi[1]; af[mt][6] = hi[2]; af[mt][7] = hi[3];
        }
        #pragma unroll
        for (int nt = 0; nt < 4; nt++) {
            i32x4 lo = *reinterpret_cast<const i32x4*>(pb[nt] + k0);
            i32x4 hi = *reinterpret_cast<const i32x4*>(pb[nt] + k0 + 16);
            bfr[nt][0] = lo[0]; bfr[nt][1] = lo[1]; bfr[nt][2] = lo[2]; bfr[nt][3] = lo[3];
            bfr[nt][4] = hi[0]; bfr[nt][5] = hi[1]; bfr[nt][6] = hi[2]; bfr[nt][7] = hi[3];
        }

        #pragma unroll
        for (int mt = 0; mt < 4; mt++)
            #pragma unroll
            for (int nt = 0; nt < 4; nt++)
                acc[mt][nt] = __builtin_amdgcn_mfma_scale_f32_16x16x128_f8f6f4(
                    af[mt], bfr[nt], acc[mt][nt],
                    0, 0,                 // cbsz=0 (A fp8 e4m3), blgp=0 (B fp8 e4m3)
                    0, 0x7F7F7F7F,        // A scale: e8m0 127 = x1.0
                    0, 0x7F7F7F7F);       // B scale: x1.0
    }

    // Epilogue (identical to R4, proven): D[m][n] at lane: n = lane&15,
    // m = quad*4 + reg (shape-determined C/D layout).
    float sqi[4][4], sqj[4];
    #pragma unroll
    for (int mt = 0; mt < 4; mt++)
        #pragma unroll
        for (int tt = 0; tt < 4; tt++)
            sqi[mt][tt] = sq[ibase + mt * 16 + quad * 4 + tt];
    #pragma unroll
    for (int nt = 0; nt < 4; nt++)
        sqj[nt] = sq[jbase + nt * 16 + lr];

    if (bi != bj) {
        // Fully-below-diagonal block: all j < i guaranteed -> no predicate
        #pragma unroll
        for (int mt = 0; mt < 4; mt++) {
            #pragma unroll
            for (int tt = 0; tt < 4; tt++) {
                int i = ibase + mt * 16 + quad * 4 + tt;
                unsigned rowoff = (unsigned)(i * (i - 1) / 2);
                #pragma unroll
                for (int nt = 0; nt < 4; nt++) {
                    int j = jbase + nt * 16 + lr;
                    float d2 = sqi[mt][tt] + sqj[nt] - 2.0f * acc[mt][nt][tt];
                    out[rowoff + (unsigned)j] = sqrtf(fmaxf(d2, 0.0f));
                }
            }
        }
    } else {
        #pragma unroll
        for (int mt = 0; mt < 4; mt++) {
            #pragma unroll
            for (int tt = 0; tt < 4; tt++) {
                int i = ibase + mt * 16 + quad * 4 + tt;
                unsigned rowoff = (unsigned)(i * (i - 1) / 2);
                #pragma unroll
                for (int nt = 0; nt < 4; nt++) {
                    int j = jbase + nt * 16 + lr;
                    if (j < i) {
                        float d2 = sqi[mt][tt] + sqj[nt] - 2.0f * acc[mt][nt][tt];
                        out[rowoff + (unsigned)j] = sqrtf(fmaxf(d2, 0.0f));
                    }
                }
            }
        }
    }
}

extern "C" void kernel_launch(void* const* d_in, const int* in_sizes, int n_in,
                              void* d_out, int out_size, void* d_ws, size_t ws_size,
                              hipStream_t stream) {
    const float* x = (const float*)d_in[0];
    float* out = (float*)d_out;

    // Workspace layout: [0, 2MB) fp8 copy of x; then 16KB of fp32 row norms.
    unsigned char* xq = (unsigned char*)d_ws;
    float* sq = (float*)((char*)d_ws + (size_t)N * D);

    prep_kernel<<<N / 4, 256, 0, stream>>>(x, xq, sq);

    int nblocks = NB * (NB + 1) / 2;  // 528 lower-triangular block pairs
    pairdist_kernel<<<nblocks, 256, 0, stream>>>(xq, sq, out);
}

// Round 6
// 81.713 us; speedup vs baseline: 1.2133x; 1.2133x over previous
//
#include <hip/hip_runtime.h>
#include <hip/hip_bf16.h>
#include <stdint.h>

#define N 4096
#define D 512
#define TM 128           // block tile rows
#define TN 64            // block tile cols
#define BK 128           // fp8 bytes (=elems) per K-chunk
#define KITERS (D / BK)  // 4

typedef float f32x4 __attribute__((ext_vector_type(4)));
typedef int   i32x8 __attribute__((ext_vector_type(8)));
typedef int   i32x4 __attribute__((ext_vector_type(4)));

// ---------------------------------------------------------------------------
// Kernel 1: fp32 -> fp8 e4m3 (OCP) conversion + fp32 row squared-norms.
// One wave per row: 512 elems / 64 lanes = 8 elems/lane (one 8B store).
// Norms are exact fp32; only the Gram term carries fp8 error.  (Proven R4.)
// ---------------------------------------------------------------------------
__global__ __launch_bounds__(256) void prep_kernel(const float* __restrict__ x,
                                                   unsigned char* __restrict__ xq,
                                                   float* __restrict__ sq) {
    int row  = blockIdx.x * 4 + (threadIdx.x >> 6);
    int lane = threadIdx.x & 63;
    const float* xr = x + (size_t)row * D + lane * 8;
    float4 v0 = *reinterpret_cast<const float4*>(xr);
    float4 v1 = *reinterpret_cast<const float4*>(xr + 4);

    int w0 = __builtin_amdgcn_cvt_pk_fp8_f32(v0.x, v0.y, 0, false);
    w0     = __builtin_amdgcn_cvt_pk_fp8_f32(v0.z, v0.w, w0, true);
    int w1 = __builtin_amdgcn_cvt_pk_fp8_f32(v1.x, v1.y, 0, false);
    w1     = __builtin_amdgcn_cvt_pk_fp8_f32(v1.z, v1.w, w1, true);
    reinterpret_cast<int2*>(xq + (size_t)row * D)[lane] = make_int2(w0, w1);

    float s = v0.x * v0.x + v0.y * v0.y + v0.z * v0.z + v0.w * v0.w +
              v1.x * v1.x + v1.y * v1.y + v1.z * v1.z + v1.w * v1.w;
    #pragma unroll
    for (int off = 32; off > 0; off >>= 1) s += __shfl_down(s, off);
    if (lane == 0) sq[row] = s;
}

// ---------------------------------------------------------------------------
// Kernel 2: lower-triangle Gram via MX-scaled fp8 MFMA (K=128, unit scales)
// + fused distance epilogue.
// R6 change vs R4: 128x64 tiles -> 1056 blocks (vs 528) to smooth the
// straggler tail (1.45x -> 1.21x at 4 resident blocks/CU). Core (fp8 glds
// XOR-swizzle, fragment layout, epilogue) identical to the proven R4 code;
// block mapping identical to the proven R3 code. LDS 24 KB/block,
// launch_bounds(256,4): acc 4x2 + frags ~= 100 VGPR -> fits the 128 cap.
// ---------------------------------------------------------------------------
__global__ __launch_bounds__(256, 4) void pairdist_kernel(const unsigned char* __restrict__ xq,
                                                          const float* __restrict__ sq,
                                                          float* __restrict__ out) {
    __shared__ __align__(16) unsigned char As[TM * BK];  // 16 KB
    __shared__ __align__(16) unsigned char Bs[TN * BK];  // 8 KB

    // Linear block id -> (bi, bj): t = bi^2 + bi + bj, 0 <= bj <= 2*bi+1.
    // Row tile bi covers rows [128*bi, +128); col tile bj covers [64*bj, +64).
    int t  = blockIdx.x;
    int bi = (int)((sqrtf(4.0f * (float)t + 1.0f) - 1.0f) * 0.5f);
    while (bi * bi + 3 * bi + 2 <= t) bi++;
    while (bi * bi + bi > t) bi--;
    int bj = t - bi * bi - bi;
    bool full = (bj < 2 * bi);  // fully below diagonal: all j < i guaranteed

    int tid  = threadIdx.x;
    int w    = tid >> 6;        // wave 0..3
    int lane = tid & 63;
    int quad = lane >> 4;       // 0..3
    int lr   = lane & 15;       // 0..15
    int wm   = w >> 1;          // wave row (0..1) -> 64 rows
    int wn   = w & 1;           // wave col (0..1) -> 32 cols

    int ibase = bi * TM + wm * 64;
    int jbase = bj * TN + wn * 32;

    f32x4 acc[4][2];
    #pragma unroll
    for (int mt = 0; mt < 4; mt++)
        #pragma unroll
        for (int nt = 0; nt < 2; nt++)
            acc[mt][nt] = (f32x4)0.0f;

    // Staging (proven R4 pattern): lane l -> row l>>3, LDS chunk l&7; source
    // chunk = (l&7) ^ (l>>3) implements the XOR swizzle so fragment b128
    // reads spread across all 8 four-bank groups. Wave w stages A rows
    // [w*32, +32) via 4 glds and B rows [w*16, +16) via 2 glds.
    int srow   = lane >> 3;                 // 0..7
    int schunk = lane & 7;                  // 16B chunk
    int sw     = ((schunk ^ srow) << 4);    // swizzled byte offset in row
    const unsigned char* ga = xq + (size_t)(bi * TM + w * 32 + srow) * D + sw;
    const unsigned char* gb = xq + (size_t)(bj * TN + w * 16 + srow) * D + sw;
    unsigned char* la = As + w * 32 * BK;   // wave-uniform LDS bases
    unsigned char* lb = Bs + w * 16 * BK;

    for (int k0 = 0; k0 < D; k0 += BK) {
        __syncthreads();   // prev iter's ds_reads done before overwrite
        #pragma unroll
        for (int g = 0; g < 4; g++)
            __builtin_amdgcn_global_load_lds(
                (const __attribute__((address_space(1))) void*)(ga + k0 + (size_t)g * 8 * D),
                (__attribute__((address_space(3))) void*)(la + g * 8 * BK), 16, 0, 0);
        #pragma unroll
        for (int g = 0; g < 2; g++)
            __builtin_amdgcn_global_load_lds(
                (const __attribute__((address_space(1))) void*)(gb + k0 + (size_t)g * 8 * D),
                (__attribute__((address_space(3))) void*)(lb + g * 8 * BK), 16, 0, 0);
        __syncthreads();   // drains vmcnt(0): staging visible

        // Fragment layout (16x16x128 f8f6f4): lane holds A[m=lr][k=quad*32+j],
        // 32 B = 2 x b128 at swizzled chunks c0, c0^1.
        int c0 = (((2 * quad) ^ (lr & 7)) << 4);
        int c1 = c0 ^ 16;
        i32x8 af[4], bfr[2];
        #pragma unroll
        for (int mt = 0; mt < 4; mt++) {
            const unsigned char* rb = As + (wm * 64 + mt * 16 + lr) * BK;
            i32x4 lo = *reinterpret_cast<const i32x4*>(rb + c0);
            i32x4 hi = *reinterpret_cast<const i32x4*>(rb + c1);
            af[mt][0] = lo[0]; af[mt][1] = lo[1]; af[mt][2] = lo[2]; af[mt][3] = lo[3];
            af[mt][4] = hi[0]; af[mt][5] = hi[1]; af[mt][6] = hi[2]; af[mt][7] = hi[3];
        }
        #pragma unroll
        for (int nt = 0; nt < 2; nt++) {
            const unsigned char* rb = Bs + (wn * 32 + nt * 16 + lr) * BK;
            i32x4 lo = *reinterpret_cast<const i32x4*>(rb + c0);
            i32x4 hi = *reinterpret_cast<const i32x4*>(rb + c1);
            bfr[nt][0] = lo[0]; bfr[nt][1] = lo[1]; bfr[nt][2] = lo[2]; bfr[nt][3] = lo[3];
            bfr[nt][4] = hi[0]; bfr[nt][5] = hi[1]; bfr[nt][6] = hi[2]; bfr[nt][7] = hi[3];
        }

        #pragma unroll
        for (int mt = 0; mt < 4; mt++)
            #pragma unroll
            for (int nt = 0; nt < 2; nt++)
                acc[mt][nt] = __builtin_amdgcn_mfma_scale_f32_16x16x128_f8f6f4(
                    af[mt], bfr[nt], acc[mt][nt],
                    0, 0,                 // cbsz=0 (A fp8 e4m3), blgp=0 (B fp8 e4m3)
                    0, 0x7F7F7F7F,        // A scale: e8m0 127 = x1.0
                    0, 0x7F7F7F7F);       // B scale: x1.0
    }

    // Epilogue (proven R4): D[m][n] at lane: n = lane&15, m = quad*4 + reg.
    float sqi[4][4], sqj[2];
    #pragma unroll
    for (int mt = 0; mt < 4; mt++)
        #pragma unroll
        for (int tt = 0; tt < 4; tt++)
            sqi[mt][tt] = sq[ibase + mt * 16 + quad * 4 + tt];
    #pragma unroll
    for (int nt = 0; nt < 2; nt++)
        sqj[nt] = sq[jbase + nt * 16 + lr];

    if (full) {
        #pragma unroll
        for (int mt = 0; mt < 4; mt++) {
            #pragma unroll
            for (int tt = 0; tt < 4; tt++) {
                int i = ibase + mt * 16 + quad * 4 + tt;
                unsigned rowoff = (unsigned)(i * (i - 1) / 2);
                #pragma unroll
                for (int nt = 0; nt < 2; nt++) {
                    int j = jbase + nt * 16 + lr;
                    float d2 = sqi[mt][tt] + sqj[nt] - 2.0f * acc[mt][nt][tt];
                    out[rowoff + (unsigned)j] = sqrtf(fmaxf(d2, 0.0f));
                }
            }
        }
    } else {
        #pragma unroll
        for (int mt = 0; mt < 4; mt++) {
            #pragma unroll
            for (int tt = 0; tt < 4; tt++) {
                int i = ibase + mt * 16 + quad * 4 + tt;
                unsigned rowoff = (unsigned)(i * (i - 1) / 2);
                #pragma unroll
                for (int nt = 0; nt < 2; nt++) {
                    int j = jbase + nt * 16 + lr;
                    if (j < i) {
                        float d2 = sqi[mt][tt] + sqj[nt] - 2.0f * acc[mt][nt][tt];
                        out[rowoff + (unsigned)j] = sqrtf(fmaxf(d2, 0.0f));
                    }
                }
            }
        }
    }
}

extern "C" void kernel_launch(void* const* d_in, const int* in_sizes, int n_in,
                              void* d_out, int out_size, void* d_ws, size_t ws_size,
                              hipStream_t stream) {
    const float* x = (const float*)d_in[0];
    float* out = (float*)d_out;

    // Workspace layout: [0, 2MB) fp8 copy of x; then 16KB of fp32 row norms.
    unsigned char* xq = (unsigned char*)d_ws;
    float* sq = (float*)((char*)d_ws + (size_t)N * D);

    prep_kernel<<<N / 4, 256, 0, stream>>>(x, xq, sq);

    // Grid: bi in [0,32) x bj in [0, 2*bi+2) -> 32^2 + 32 = 1056 blocks
    int nblocks = 32 * 32 + 32;
    pairdist_kernel<<<nblocks, 256, 0, stream>>>(xq, sq, out);
}